// Round 1
// baseline (4489.352 us; speedup 1.0000x reference)
//
#include <hip/hip_runtime.h>
#include <math.h>

#define N_NODES 100000
#define N_EDGES 1600000
#define NFEAT 64
#define NCLASS 40

// ---------------------------------------------------------------------------
// agg[dst[e]] += in[src[e]]  (16 lanes per edge, float4 each)
// ---------------------------------------------------------------------------
__global__ __launch_bounds__(256) void scatter_add_k(
    const float* __restrict__ in,
    const int* __restrict__ src,
    const int* __restrict__ dst,
    float* __restrict__ agg) {
  long long gid = (long long)blockIdx.x * blockDim.x + threadIdx.x;
  int e = (int)(gid >> 4);
  int c = ((int)gid & 15) << 2;           // feature offset 0..60 step 4
  if (e >= N_EDGES) return;
  int s = src[e];
  int d = dst[e];
  const float4 v = *reinterpret_cast<const float4*>(in + (long long)s * NFEAT + c);
  float* p = agg + (long long)d * NFEAT + c;
  atomicAdd(p + 0, v.x);
  atomicAdd(p + 1, v.y);
  atomicAdd(p + 2, v.z);
  atomicAdd(p + 3, v.w);
}

// ---------------------------------------------------------------------------
// out[r][c] = relu( sum_k (x[r][k] + agg[r][k]) * W[k][c] + b[c] )
// 64-row tile per block, 256 threads: thread t -> col c=t&63, rows rb*16..+16
// Safe to alias out == agg: each block reads only its own rows (staged to LDS
// before __syncthreads) and writes only those same rows.
// ---------------------------------------------------------------------------
__global__ __launch_bounds__(256) void linear_relu_k(
    const float* __restrict__ x, const float* __restrict__ agg,
    const float* __restrict__ W, const float* __restrict__ b,
    float* __restrict__ out) {
  __shared__ float sIn[64][65];
  __shared__ float sW[64][64];
  int r0 = blockIdx.x * 64;
  int t = threadIdx.x;
  for (int i = t; i < 64 * 64; i += 256) sW[i >> 6][i & 63] = W[i];
  for (int i = t; i < 64 * 64; i += 256) {
    int r = i >> 6, k = i & 63;
    int gr = r0 + r;
    float v = 0.f;
    if (gr < N_NODES) {
      long long idx = (long long)gr * NFEAT + k;
      v = x[idx] + agg[idx];
    }
    sIn[r][k] = v;
  }
  __syncthreads();

  int c  = t & 63;
  int rb = t >> 6;  // 0..3
  float acc[16];
#pragma unroll
  for (int i = 0; i < 16; ++i) acc[i] = 0.f;
#pragma unroll
  for (int k = 0; k < 64; ++k) {
    float wkc = sW[k][c];
#pragma unroll
    for (int i = 0; i < 16; ++i)
      acc[i] = fmaf(sIn[rb * 16 + i][k], wkc, acc[i]);
  }
  float bias = b[c];
#pragma unroll
  for (int i = 0; i < 16; ++i) {
    int gr = r0 + rb * 16 + i;
    if (gr < N_NODES)
      out[(long long)gr * NFEAT + c] = fmaxf(acc[i] + bias, 0.f);
  }
}

// ---------------------------------------------------------------------------
// logits = h @ Wf + bf ; out = log_softmax(logits)  — one wave per row
// ---------------------------------------------------------------------------
__global__ __launch_bounds__(256) void final_logsoftmax_k(
    const float* __restrict__ h, const float* __restrict__ Wf,
    const float* __restrict__ bf, float* __restrict__ out) {
  __shared__ float sW[NFEAT * NCLASS];  // [k][c]
  __shared__ float sB[NCLASS];
  int t = threadIdx.x;
  for (int i = t; i < NFEAT * NCLASS; i += 256) sW[i] = Wf[i];
  if (t < NCLASS) sB[t] = bf[t];
  __syncthreads();

  int wave = t >> 6;
  int lane = t & 63;
  int row = blockIdx.x * 4 + wave;
  if (row >= N_NODES) return;

  const float* hr = h + (long long)row * NFEAT;
  float rowval = hr[lane];                 // lane k holds h[row][k], coalesced
  int cl = lane < NCLASS ? lane : NCLASS - 1;
  float acc = sB[cl];
#pragma unroll
  for (int k = 0; k < NFEAT; ++k) {
    float hv = __shfl(rowval, k);
    acc = fmaf(hv, sW[k * NCLASS + cl], acc);
  }
  float logit = acc;
  float m = (lane < NCLASS) ? logit : -INFINITY;
#pragma unroll
  for (int off = 32; off; off >>= 1) m = fmaxf(m, __shfl_xor(m, off));
  float ex = (lane < NCLASS) ? expf(logit - m) : 0.f;
  float s = ex;
#pragma unroll
  for (int off = 32; off; off >>= 1) s += __shfl_xor(s, off);
  float lse = m + logf(s);
  if (lane < NCLASS) out[(long long)row * NCLASS + lane] = logit - lse;
}

// ---------------------------------------------------------------------------
extern "C" void kernel_launch(void* const* d_in, const int* in_sizes, int n_in,
                              void* d_out, int out_size, void* d_ws, size_t ws_size,
                              hipStream_t stream) {
  const float* x  = (const float*)d_in[0];
  const int*   ei = (const int*)d_in[1];       // [2, N_EDGES] int32
  const float* W1 = (const float*)d_in[2];
  const float* b1 = (const float*)d_in[3];
  const float* W2 = (const float*)d_in[4];
  const float* b2 = (const float*)d_in[5];
  const float* Wf = (const float*)d_in[6];
  const float* bf = (const float*)d_in[7];
  float* out = (float*)d_out;

  const int* src = ei;
  const int* dst = ei + N_EDGES;

  const size_t featBytes = (size_t)N_NODES * NFEAT * sizeof(float);  // 25.6 MB
  float* bufA = (float*)d_ws;                                 // agg / h2
  float* bufB = (float*)((char*)d_ws + featBytes);            // h1

  const int scatterBlocks = (N_EDGES * 16 + 255) / 256;       // 100000
  const int linBlocks = (N_NODES + 63) / 64;                  // 1563
  const int finBlocks = (N_NODES + 3) / 4;                    // 25000

  // Layer 1
  hipMemsetAsync(bufA, 0, featBytes, stream);
  scatter_add_k<<<scatterBlocks, 256, 0, stream>>>(x, src, dst, bufA);
  linear_relu_k<<<linBlocks, 256, 0, stream>>>(x, bufA, W1, b1, bufB);

  // Layer 2
  hipMemsetAsync(bufA, 0, featBytes, stream);
  scatter_add_k<<<scatterBlocks, 256, 0, stream>>>(bufB, src, dst, bufA);
  linear_relu_k<<<linBlocks, 256, 0, stream>>>(bufB, bufA, W2, b2, bufA);  // h2 over agg

  // Final layer + log_softmax
  final_logsoftmax_k<<<finBlocks, 256, 0, stream>>>(bufA, Wf, bf, out);
}

// Round 4
// 2573.487 us; speedup vs baseline: 1.7445x; 1.7445x over previous
//
#include <hip/hip_runtime.h>
#include <math.h>

#define N_NODES 100000
#define N_EDGES 1600000
#define NFEAT 64
#define NCLASS 40

// ---------------------------------------------------------------------------
// CSR build: deg histogram over dst
// ---------------------------------------------------------------------------
__global__ __launch_bounds__(256) void hist_k(const int* __restrict__ dst,
                                              int* __restrict__ deg) {
  int e = blockIdx.x * 256 + threadIdx.x;
  if (e < N_EDGES) atomicAdd(&deg[dst[e]], 1);
}

// One-block exclusive scan of deg -> offs (and copy into cursor)
__global__ __launch_bounds__(1024) void scan_k(const int* __restrict__ deg,
                                               int* __restrict__ offs,
                                               int* __restrict__ cursor) {
  __shared__ int part[1024];
  int t = threadIdx.x;
  const int CH = (N_NODES + 1023) / 1024;  // 98
  int beg = t * CH;
  int end = min(beg + CH, N_NODES);
  int s = 0;
  for (int i = beg; i < end; ++i) s += deg[i];
  part[t] = s;
  __syncthreads();
  for (int off = 1; off < 1024; off <<= 1) {
    int add = (t >= off) ? part[t - off] : 0;
    __syncthreads();
    part[t] += add;
    __syncthreads();
  }
  int run = (t == 0) ? 0 : part[t - 1];
  for (int i = beg; i < end; ++i) {
    offs[i] = run;
    cursor[i] = run;
    run += deg[i];
  }
  if (t == 1023) offs[N_NODES] = run;  // == N_EDGES
}

__global__ __launch_bounds__(256) void fill_csr_k(const int* __restrict__ src,
                                                  const int* __restrict__ dst,
                                                  int* __restrict__ cursor,
                                                  int* __restrict__ csr) {
  int e = blockIdx.x * 256 + threadIdx.x;
  if (e < N_EDGES) {
    int d = dst[e];
    int pos = atomicAdd(&cursor[d], 1);
    csr[pos] = src[e];
  }
}

// ---------------------------------------------------------------------------
// Fused GIN layer: out[r] = relu( (h[r] + sum_{s in N(r)} h[s]) @ W + b )
// Block = 256 threads = 4 waves, 64 rows per block.
// Phase 1: wave wv gathers rows [wv*16, wv*16+16); lane c owns feature c.
// Phase 2: 64x64 @ 64x64 tile GEMM from LDS (wave-broadcast sIn reads).
// out must NOT alias h (gather reads arbitrary rows).
// ---------------------------------------------------------------------------
__global__ __launch_bounds__(256) void gin_layer_k(
    const float* __restrict__ h, const int* __restrict__ offs,
    const int* __restrict__ csr, const float* __restrict__ W,
    const float* __restrict__ b, float* __restrict__ out) {
  __shared__ float sIn[64][65];
  __shared__ float sW[64][64];
  int r0 = blockIdx.x * 64;
  int t = threadIdx.x;
  int c = t & 63;
  int wv = t >> 6;  // wave id 0..3

  for (int i = t; i < 64 * 64; i += 256) sW[i >> 6][i & 63] = W[i];

  // Phase 1: gather + self term
  for (int i = 0; i < 16; ++i) {
    int r = wv * 16 + i;
    int gr = r0 + r;
    float acc = 0.f;
    if (gr < N_NODES) {
      acc = h[(long long)gr * NFEAT + c];
      int beg = offs[gr], end = offs[gr + 1];
      int e = beg;
      for (; e + 4 <= end; e += 4) {
        int s0 = csr[e], s1 = csr[e + 1], s2 = csr[e + 2], s3 = csr[e + 3];
        float v0 = h[(long long)s0 * NFEAT + c];
        float v1 = h[(long long)s1 * NFEAT + c];
        float v2 = h[(long long)s2 * NFEAT + c];
        float v3 = h[(long long)s3 * NFEAT + c];
        acc += (v0 + v1) + (v2 + v3);
      }
      for (; e < end; ++e) acc += h[(long long)csr[e] * NFEAT + c];
    }
    sIn[r][c] = acc;
  }
  __syncthreads();

  // Phase 2: tile GEMM
  int rb = t >> 6;  // 0..3
  float acc[16];
#pragma unroll
  for (int i = 0; i < 16; ++i) acc[i] = 0.f;
#pragma unroll
  for (int k = 0; k < 64; ++k) {
    float wkc = sW[k][c];
#pragma unroll
    for (int i = 0; i < 16; ++i)
      acc[i] = fmaf(sIn[rb * 16 + i][k], wkc, acc[i]);
  }
  float bias = b[c];
#pragma unroll
  for (int i = 0; i < 16; ++i) {
    int gr = r0 + rb * 16 + i;
    if (gr < N_NODES)
      out[(long long)gr * NFEAT + c] = fmaxf(acc[i] + bias, 0.f);
  }
}

// ---------------------------------------------------------------------------
// logits = h @ Wf + bf ; out = log_softmax(logits) — one wave per row,
// grid-stride over rows to amortize the Wf LDS load.
// ---------------------------------------------------------------------------
__global__ __launch_bounds__(256) void final_logsoftmax_k(
    const float* __restrict__ h, const float* __restrict__ Wf,
    const float* __restrict__ bf, float* __restrict__ out) {
  __shared__ float sW[NFEAT * NCLASS];  // [k][c]
  __shared__ float sB[NCLASS];
  int t = threadIdx.x;
  for (int i = t; i < NFEAT * NCLASS; i += 256) sW[i] = Wf[i];
  if (t < NCLASS) sB[t] = bf[t];
  __syncthreads();

  int wave = t >> 6;
  int lane = t & 63;
  int cl = lane < NCLASS ? lane : NCLASS - 1;

  for (int row = blockIdx.x * 4 + wave; row < N_NODES;
       row += gridDim.x * 4) {
    const float* hr = h + (long long)row * NFEAT;
    float rowval = hr[lane];  // lane k holds h[row][k], coalesced
    float acc = sB[cl];
#pragma unroll
    for (int k = 0; k < NFEAT; ++k) {
      float hv = __shfl(rowval, k);
      acc = fmaf(hv, sW[k * NCLASS + cl], acc);
    }
    float logit = acc;
    float m = (lane < NCLASS) ? logit : -INFINITY;
#pragma unroll
    for (int off = 32; off; off >>= 1) m = fmaxf(m, __shfl_xor(m, off));
    float ex = (lane < NCLASS) ? expf(logit - m) : 0.f;
    float s = ex;
#pragma unroll
    for (int off = 32; off; off >>= 1) s += __shfl_xor(s, off);
    float lse = m + logf(s);
    if (lane < NCLASS) out[(long long)row * NCLASS + lane] = logit - lse;
  }
}

// ---------------------------------------------------------------------------
extern "C" void kernel_launch(void* const* d_in, const int* in_sizes, int n_in,
                              void* d_out, int out_size, void* d_ws, size_t ws_size,
                              hipStream_t stream) {
  const float* x  = (const float*)d_in[0];
  const int*   ei = (const int*)d_in[1];  // [2, N_EDGES] as int32
  const float* W1 = (const float*)d_in[2];
  const float* b1 = (const float*)d_in[3];
  const float* W2 = (const float*)d_in[4];
  const float* b2 = (const float*)d_in[5];
  const float* Wf = (const float*)d_in[6];
  const float* bf = (const float*)d_in[7];
  float* out = (float*)d_out;

  const int* src = ei;
  const int* dst = ei + N_EDGES;

  float* bufA = (float*)d_ws;                       // h2
  float* bufB = bufA + (size_t)N_NODES * NFEAT;     // h1
  int* deg    = (int*)(bufB + (size_t)N_NODES * NFEAT);
  int* offs   = deg + N_NODES;                      // N_NODES+1
  int* cursor = offs + N_NODES + 1;
  int* csr    = cursor + N_NODES;                   // N_EDGES

  const int edgeBlocks = (N_EDGES + 255) / 256;  // 6250
  const int linBlocks  = (N_NODES + 63) / 64;    // 1563
  const int finBlocks  = 2048;

  // Build dst-CSR (once; reused by both layers)
  hipMemsetAsync(deg, 0, N_NODES * sizeof(int), stream);
  hist_k<<<edgeBlocks, 256, 0, stream>>>(dst, deg);
  scan_k<<<1, 1024, 0, stream>>>(deg, offs, cursor);
  fill_csr_k<<<edgeBlocks, 256, 0, stream>>>(src, dst, cursor, csr);

  // Layer 1: x -> bufB
  gin_layer_k<<<linBlocks, 256, 0, stream>>>(x, offs, csr, W1, b1, bufB);
  // Layer 2: bufB -> bufA
  gin_layer_k<<<linBlocks, 256, 0, stream>>>(bufB, offs, csr, W2, b2, bufA);
  // Final + log_softmax
  final_logsoftmax_k<<<finBlocks, 256, 0, stream>>>(bufA, Wf, bf, out);
}

// Round 5
// 764.143 us; speedup vs baseline: 5.8750x; 3.3678x over previous
//
#include <hip/hip_runtime.h>
#include <math.h>

#define N_NODES 100000
#define N_EDGES 1600000
#define NFEAT 64
#define NCLASS 40

// ---------------------------------------------------------------------------
// CSR build: deg histogram over dst
// ---------------------------------------------------------------------------
__global__ __launch_bounds__(256) void hist_k(const int* __restrict__ dst,
                                              int* __restrict__ deg) {
  int e = blockIdx.x * 256 + threadIdx.x;
  if (e < N_EDGES) atomicAdd(&deg[dst[e]], 1);
}

// One-block exclusive scan of deg -> offs (and copy into cursor)
__global__ __launch_bounds__(1024) void scan_k(const int* __restrict__ deg,
                                               int* __restrict__ offs,
                                               int* __restrict__ cursor) {
  __shared__ int part[1024];
  int t = threadIdx.x;
  const int CH = (N_NODES + 1023) / 1024;  // 98
  int beg = t * CH;
  int end = min(beg + CH, N_NODES);
  int s = 0;
  for (int i = beg; i < end; ++i) s += deg[i];
  part[t] = s;
  __syncthreads();
  for (int off = 1; off < 1024; off <<= 1) {
    int add = (t >= off) ? part[t - off] : 0;
    __syncthreads();
    part[t] += add;
    __syncthreads();
  }
  int run = (t == 0) ? 0 : part[t - 1];
  for (int i = beg; i < end; ++i) {
    offs[i] = run;
    cursor[i] = run;
    run += deg[i];
  }
  if (t == 1023) offs[N_NODES] = run;  // == N_EDGES
}

__global__ __launch_bounds__(256) void fill_csr_k(const int* __restrict__ src,
                                                  const int* __restrict__ dst,
                                                  int* __restrict__ cursor,
                                                  int* __restrict__ csr) {
  int e = blockIdx.x * 256 + threadIdx.x;
  if (e < N_EDGES) {
    int d = dst[e];
    int pos = atomicAdd(&cursor[d], 1);
    csr[pos] = src[e];
  }
}

// ---------------------------------------------------------------------------
// Gather: agg[r] = h[r] + sum_{s in N(r)} h[s]
// One wave per node. Lanes = 4 groups x 16 lanes; group g handles every 4th
// edge, lane l covers features [4l, 4l+4) via float4 -> 4 independent 256B
// row-read streams in flight per wave. Cross-group reduce via shfl_xor.
// Low VGPR -> high occupancy -> latency hiding.
// ---------------------------------------------------------------------------
__global__ __launch_bounds__(256) void gather_k(
    const float* __restrict__ h, const int* __restrict__ offs,
    const int* __restrict__ csr, float* __restrict__ agg) {
  int t = threadIdx.x;
  int wv = t >> 6;
  int lane = t & 63;
  int g = lane >> 4;   // edge-group 0..3
  int l = lane & 15;   // feature quad 0..15
  int node = blockIdx.x * 4 + wv;
  if (node >= N_NODES) return;

  int beg = offs[node], end = offs[node + 1];
  float ax = 0.f, ay = 0.f, az = 0.f, aw = 0.f;
  for (int e = beg + g; e < end; e += 4) {
    int s = csr[e];
    const float4 v =
        *reinterpret_cast<const float4*>(h + (size_t)s * NFEAT + (l << 2));
    ax += v.x; ay += v.y; az += v.z; aw += v.w;
  }
  // reduce across the 4 groups (lanes l, l+16, l+32, l+48)
  ax += __shfl_xor(ax, 16); ay += __shfl_xor(ay, 16);
  az += __shfl_xor(az, 16); aw += __shfl_xor(aw, 16);
  ax += __shfl_xor(ax, 32); ay += __shfl_xor(ay, 32);
  az += __shfl_xor(az, 32); aw += __shfl_xor(aw, 32);

  if (g == 0) {
    const float4 self =
        *reinterpret_cast<const float4*>(h + (size_t)node * NFEAT + (l << 2));
    float4 o;
    o.x = ax + self.x; o.y = ay + self.y;
    o.z = az + self.z; o.w = aw + self.w;
    *reinterpret_cast<float4*>(agg + (size_t)node * NFEAT + (l << 2)) = o;
  }
}

// ---------------------------------------------------------------------------
// out[r][c] = relu( sum_k in[r][k] * W[k][c] + b[c] )
// 32-row tile per block, 256 threads: thread t -> col c=t&63, 8 rows.
// ---------------------------------------------------------------------------
__global__ __launch_bounds__(256) void linear_relu_k(
    const float* __restrict__ in, const float* __restrict__ W,
    const float* __restrict__ b, float* __restrict__ out) {
  __shared__ float sIn[32][64];
  __shared__ float sW[64][64];
  int r0 = blockIdx.x * 32;
  int t = threadIdx.x;
  for (int i = t; i < 64 * 64; i += 256) sW[i >> 6][i & 63] = W[i];
  // load 32 rows x 64 feats as float4: 512 quads
  for (int i = t; i < 512; i += 256) {
    int r = i >> 4, q = i & 15;
    float4 v = *reinterpret_cast<const float4*>(
        in + (size_t)(r0 + r) * NFEAT + (q << 2));
    *reinterpret_cast<float4*>(&sIn[r][q << 2]) = v;
  }
  __syncthreads();

  int c = t & 63;
  int rb = t >> 6;  // 0..3 -> rows rb*8..rb*8+8
  float acc[8];
#pragma unroll
  for (int i = 0; i < 8; ++i) acc[i] = 0.f;
#pragma unroll
  for (int k = 0; k < 64; ++k) {
    float wkc = sW[k][c];
#pragma unroll
    for (int i = 0; i < 8; ++i)
      acc[i] = fmaf(sIn[rb * 8 + i][k], wkc, acc[i]);
  }
  float bias = b[c];
#pragma unroll
  for (int i = 0; i < 8; ++i) {
    int gr = r0 + rb * 8 + i;
    out[(size_t)gr * NFEAT + c] = fmaxf(acc[i] + bias, 0.f);
  }
}

// ---------------------------------------------------------------------------
// logits = h @ Wf + bf ; out = log_softmax(logits) — one wave per row,
// grid-stride over rows to amortize the Wf LDS load.
// ---------------------------------------------------------------------------
__global__ __launch_bounds__(256) void final_logsoftmax_k(
    const float* __restrict__ h, const float* __restrict__ Wf,
    const float* __restrict__ bf, float* __restrict__ out) {
  __shared__ float sW[NFEAT * NCLASS];  // [k][c]
  __shared__ float sB[NCLASS];
  int t = threadIdx.x;
  for (int i = t; i < NFEAT * NCLASS; i += 256) sW[i] = Wf[i];
  if (t < NCLASS) sB[t] = bf[t];
  __syncthreads();

  int wave = t >> 6;
  int lane = t & 63;
  int cl = lane < NCLASS ? lane : NCLASS - 1;

  for (int row = blockIdx.x * 4 + wave; row < N_NODES;
       row += gridDim.x * 4) {
    const float* hr = h + (size_t)row * NFEAT;
    float rowval = hr[lane];  // lane k holds h[row][k], coalesced
    float acc = sB[cl];
#pragma unroll
    for (int k = 0; k < NFEAT; ++k) {
      float hv = __shfl(rowval, k);
      acc = fmaf(hv, sW[k * NCLASS + cl], acc);
    }
    float logit = acc;
    float m = (lane < NCLASS) ? logit : -INFINITY;
#pragma unroll
    for (int off = 32; off; off >>= 1) m = fmaxf(m, __shfl_xor(m, off));
    float ex = (lane < NCLASS) ? expf(logit - m) : 0.f;
    float s = ex;
#pragma unroll
    for (int off = 32; off; off >>= 1) s += __shfl_xor(s, off);
    float lse = m + logf(s);
    if (lane < NCLASS) out[(size_t)row * NCLASS + lane] = logit - lse;
  }
}

// ---------------------------------------------------------------------------
extern "C" void kernel_launch(void* const* d_in, const int* in_sizes, int n_in,
                              void* d_out, int out_size, void* d_ws, size_t ws_size,
                              hipStream_t stream) {
  const float* x  = (const float*)d_in[0];
  const int*   ei = (const int*)d_in[1];  // [2, N_EDGES] as int32
  const float* W1 = (const float*)d_in[2];
  const float* b1 = (const float*)d_in[3];
  const float* W2 = (const float*)d_in[4];
  const float* b2 = (const float*)d_in[5];
  const float* Wf = (const float*)d_in[6];
  const float* bf = (const float*)d_in[7];
  float* out = (float*)d_out;

  const int* src = ei;
  const int* dst = ei + N_EDGES;

  const size_t featElems = (size_t)N_NODES * NFEAT;
  float* bufA = (float*)d_ws;            // agg1 / h2
  float* bufB = bufA + featElems;        // h1
  float* bufC = bufB + featElems;        // agg2
  int* deg    = (int*)(bufC + featElems);
  int* offs   = deg + N_NODES;           // N_NODES+1
  int* cursor = offs + N_NODES + 1;
  int* csr    = cursor + N_NODES;        // N_EDGES

  const int edgeBlocks   = (N_EDGES + 255) / 256;  // 6250
  const int gatherBlocks = (N_NODES + 3) / 4;      // 25000
  const int linBlocks    = (N_NODES + 31) / 32;    // 3125
  const int finBlocks    = 2048;

  // Build dst-CSR (once; reused by both layers)
  hipMemsetAsync(deg, 0, N_NODES * sizeof(int), stream);
  hist_k<<<edgeBlocks, 256, 0, stream>>>(dst, deg);
  scan_k<<<1, 1024, 0, stream>>>(deg, offs, cursor);
  fill_csr_k<<<edgeBlocks, 256, 0, stream>>>(src, dst, cursor, csr);

  // Layer 1: x --gather--> bufA --linear--> bufB (h1)
  gather_k<<<gatherBlocks, 256, 0, stream>>>(x, offs, csr, bufA);
  linear_relu_k<<<linBlocks, 256, 0, stream>>>(bufA, W1, b1, bufB);

  // Layer 2: bufB --gather--> bufC --linear--> bufA (h2)
  gather_k<<<gatherBlocks, 256, 0, stream>>>(bufB, offs, csr, bufC);
  linear_relu_k<<<linBlocks, 256, 0, stream>>>(bufC, W2, b2, bufA);

  // Final + log_softmax
  final_logsoftmax_k<<<finBlocks, 256, 0, stream>>>(bufA, Wf, bf, out);
}

// Round 6
// 550.930 us; speedup vs baseline: 8.1487x; 1.3870x over previous
//
#include <hip/hip_runtime.h>
#include <math.h>

#define N_NODES 100000
#define N_EDGES 1600000
#define NFEAT 64
#define NCLASS 40

#define SCAN_CHUNK 1024
#define SCAN_BLOCKS ((N_NODES + SCAN_CHUNK - 1) / SCAN_CHUNK)  // 98

// ---------------------------------------------------------------------------
// CSR build: deg histogram over dst
// ---------------------------------------------------------------------------
__global__ __launch_bounds__(256) void hist_k(const int* __restrict__ dst,
                                              int* __restrict__ deg) {
  int e = blockIdx.x * 256 + threadIdx.x;
  if (e < N_EDGES) atomicAdd(&deg[dst[e]], 1);
}

// Pass 1: per-block chunk sums
__global__ __launch_bounds__(256) void scan_partial_k(
    const int* __restrict__ deg, int* __restrict__ blockSums) {
  __shared__ int red[256];
  int b = blockIdx.x, t = threadIdx.x;
  int base = b * SCAN_CHUNK;
  int s = 0;
  for (int i = t; i < SCAN_CHUNK; i += 256) {
    int idx = base + i;
    if (idx < N_NODES) s += deg[idx];
  }
  red[t] = s;
  __syncthreads();
  for (int off = 128; off; off >>= 1) {
    if (t < off) red[t] += red[t + off];
    __syncthreads();
  }
  if (t == 0) blockSums[b] = red[0];
}

// Pass 2: one small block scans the 98 partials (in place -> exclusive),
// writes offs[N_NODES] = total
__global__ __launch_bounds__(128) void scan_sums_k(int* __restrict__ blockSums,
                                                   int* __restrict__ offs) {
  __shared__ int part[128];
  int t = threadIdx.x;
  int v = (t < SCAN_BLOCKS) ? blockSums[t] : 0;
  part[t] = v;
  __syncthreads();
  for (int off = 1; off < 128; off <<= 1) {
    int add = (t >= off) ? part[t - off] : 0;
    __syncthreads();
    part[t] += add;
    __syncthreads();
  }
  if (t < SCAN_BLOCKS) blockSums[t] = (t == 0) ? 0 : part[t - 1];
  if (t == 127) offs[N_NODES] = part[127];  // == N_EDGES
}

// Pass 3: intra-chunk exclusive scan + block prefix -> offs, cursor
__global__ __launch_bounds__(256) void scan_final_k(
    const int* __restrict__ deg, const int* __restrict__ blockOffs,
    int* __restrict__ offs, int* __restrict__ cursor) {
  __shared__ int part[256];
  int b = blockIdx.x, t = threadIdx.x;
  int base = b * SCAN_CHUNK + t * 4;  // thread t owns 4 consecutive elements
  int v0 = 0, v1 = 0, v2 = 0, v3 = 0;
  if (base + 3 < N_NODES) {
    v0 = deg[base]; v1 = deg[base + 1]; v2 = deg[base + 2]; v3 = deg[base + 3];
  } else {
    if (base + 0 < N_NODES) v0 = deg[base + 0];
    if (base + 1 < N_NODES) v1 = deg[base + 1];
    if (base + 2 < N_NODES) v2 = deg[base + 2];
    if (base + 3 < N_NODES) v3 = deg[base + 3];
  }
  part[t] = v0 + v1 + v2 + v3;
  __syncthreads();
  for (int off = 1; off < 256; off <<= 1) {
    int add = (t >= off) ? part[t - off] : 0;
    __syncthreads();
    part[t] += add;
    __syncthreads();
  }
  int run = blockOffs[b] + ((t == 0) ? 0 : part[t - 1]);
  if (base + 0 < N_NODES) { offs[base + 0] = run; cursor[base + 0] = run; run += v0; }
  if (base + 1 < N_NODES) { offs[base + 1] = run; cursor[base + 1] = run; run += v1; }
  if (base + 2 < N_NODES) { offs[base + 2] = run; cursor[base + 2] = run; run += v2; }
  if (base + 3 < N_NODES) { offs[base + 3] = run; cursor[base + 3] = run; run += v3; }
}

__global__ __launch_bounds__(256) void fill_csr_k(const int* __restrict__ src,
                                                  const int* __restrict__ dst,
                                                  int* __restrict__ cursor,
                                                  int* __restrict__ csr) {
  int e = blockIdx.x * 256 + threadIdx.x;
  if (e < N_EDGES) {
    int d = dst[e];
    int pos = atomicAdd(&cursor[d], 1);
    csr[pos] = src[e];
  }
}

// ---------------------------------------------------------------------------
// Gather: agg[r] = h[r] + sum_{s in N(r)} h[s]
// One wave per node. Lanes = 4 groups x 16 lanes; group g handles every 4th
// edge, lane l covers features [4l, 4l+4) via float4 -> 4 independent 256B
// row-read streams in flight per wave. Cross-group reduce via shfl_xor.
// ---------------------------------------------------------------------------
__global__ __launch_bounds__(256) void gather_k(
    const float* __restrict__ h, const int* __restrict__ offs,
    const int* __restrict__ csr, float* __restrict__ agg) {
  int t = threadIdx.x;
  int wv = t >> 6;
  int lane = t & 63;
  int g = lane >> 4;   // edge-group 0..3
  int l = lane & 15;   // feature quad 0..15
  int node = blockIdx.x * 4 + wv;
  if (node >= N_NODES) return;

  int beg = offs[node], end = offs[node + 1];
  float ax = 0.f, ay = 0.f, az = 0.f, aw = 0.f;
  for (int e = beg + g; e < end; e += 4) {
    int s = csr[e];
    const float4 v =
        *reinterpret_cast<const float4*>(h + (size_t)s * NFEAT + (l << 2));
    ax += v.x; ay += v.y; az += v.z; aw += v.w;
  }
  ax += __shfl_xor(ax, 16); ay += __shfl_xor(ay, 16);
  az += __shfl_xor(az, 16); aw += __shfl_xor(aw, 16);
  ax += __shfl_xor(ax, 32); ay += __shfl_xor(ay, 32);
  az += __shfl_xor(az, 32); aw += __shfl_xor(aw, 32);

  if (g == 0) {
    const float4 self =
        *reinterpret_cast<const float4*>(h + (size_t)node * NFEAT + (l << 2));
    float4 o;
    o.x = ax + self.x; o.y = ay + self.y;
    o.z = az + self.z; o.w = aw + self.w;
    *reinterpret_cast<float4*>(agg + (size_t)node * NFEAT + (l << 2)) = o;
  }
}

// ---------------------------------------------------------------------------
// out[r][c] = relu( sum_k in[r][k] * W[k][c] + b[c] )
// 32-row tile per block, 256 threads: thread t -> col c=t&63, 8 rows.
// ---------------------------------------------------------------------------
__global__ __launch_bounds__(256) void linear_relu_k(
    const float* __restrict__ in, const float* __restrict__ W,
    const float* __restrict__ b, float* __restrict__ out) {
  __shared__ float sIn[32][64];
  __shared__ float sW[64][64];
  int r0 = blockIdx.x * 32;
  int t = threadIdx.x;
  for (int i = t; i < 64 * 64; i += 256) sW[i >> 6][i & 63] = W[i];
  for (int i = t; i < 512; i += 256) {
    int r = i >> 4, q = i & 15;
    float4 v = *reinterpret_cast<const float4*>(
        in + (size_t)(r0 + r) * NFEAT + (q << 2));
    *reinterpret_cast<float4*>(&sIn[r][q << 2]) = v;
  }
  __syncthreads();

  int c = t & 63;
  int rb = t >> 6;  // 0..3 -> rows rb*8..rb*8+8
  float acc[8];
#pragma unroll
  for (int i = 0; i < 8; ++i) acc[i] = 0.f;
#pragma unroll
  for (int k = 0; k < 64; ++k) {
    float wkc = sW[k][c];
#pragma unroll
    for (int i = 0; i < 8; ++i)
      acc[i] = fmaf(sIn[rb * 8 + i][k], wkc, acc[i]);
  }
  float bias = b[c];
#pragma unroll
  for (int i = 0; i < 8; ++i) {
    int gr = r0 + rb * 8 + i;
    out[(size_t)gr * NFEAT + c] = fmaxf(acc[i] + bias, 0.f);
  }
}

// ---------------------------------------------------------------------------
// logits = h @ Wf + bf ; out = log_softmax(logits) — one wave per row,
// grid-stride over rows to amortize the Wf LDS load.
// ---------------------------------------------------------------------------
__global__ __launch_bounds__(256) void final_logsoftmax_k(
    const float* __restrict__ h, const float* __restrict__ Wf,
    const float* __restrict__ bf, float* __restrict__ out) {
  __shared__ float sW[NFEAT * NCLASS];  // [k][c]
  __shared__ float sB[NCLASS];
  int t = threadIdx.x;
  for (int i = t; i < NFEAT * NCLASS; i += 256) sW[i] = Wf[i];
  if (t < NCLASS) sB[t] = bf[t];
  __syncthreads();

  int wave = t >> 6;
  int lane = t & 63;
  int cl = lane < NCLASS ? lane : NCLASS - 1;

  for (int row = blockIdx.x * 4 + wave; row < N_NODES;
       row += gridDim.x * 4) {
    const float* hr = h + (size_t)row * NFEAT;
    float rowval = hr[lane];  // lane k holds h[row][k], coalesced
    float acc = sB[cl];
#pragma unroll
    for (int k = 0; k < NFEAT; ++k) {
      float hv = __shfl(rowval, k);
      acc = fmaf(hv, sW[k * NCLASS + cl], acc);
    }
    float logit = acc;
    float m = (lane < NCLASS) ? logit : -INFINITY;
#pragma unroll
    for (int off = 32; off; off >>= 1) m = fmaxf(m, __shfl_xor(m, off));
    float ex = (lane < NCLASS) ? expf(logit - m) : 0.f;
    float s = ex;
#pragma unroll
    for (int off = 32; off; off >>= 1) s += __shfl_xor(s, off);
    float lse = m + logf(s);
    if (lane < NCLASS) out[(size_t)row * NCLASS + lane] = logit - lse;
  }
}

// ---------------------------------------------------------------------------
extern "C" void kernel_launch(void* const* d_in, const int* in_sizes, int n_in,
                              void* d_out, int out_size, void* d_ws, size_t ws_size,
                              hipStream_t stream) {
  const float* x  = (const float*)d_in[0];
  const int*   ei = (const int*)d_in[1];  // [2, N_EDGES] as int32
  const float* W1 = (const float*)d_in[2];
  const float* b1 = (const float*)d_in[3];
  const float* W2 = (const float*)d_in[4];
  const float* b2 = (const float*)d_in[5];
  const float* Wf = (const float*)d_in[6];
  const float* bf = (const float*)d_in[7];
  float* out = (float*)d_out;

  const int* src = ei;
  const int* dst = ei + N_EDGES;

  const size_t featElems = (size_t)N_NODES * NFEAT;
  float* bufA = (float*)d_ws;            // agg1 / h2
  float* bufB = bufA + featElems;        // h1
  float* bufC = bufB + featElems;        // agg2
  int* deg       = (int*)(bufC + featElems);
  int* offs      = deg + N_NODES;        // N_NODES+1
  int* cursor    = offs + N_NODES + 1;
  int* blockSums = cursor + N_NODES;     // SCAN_BLOCKS
  int* csr       = blockSums + 128;      // N_EDGES

  const int edgeBlocks   = (N_EDGES + 255) / 256;  // 6250
  const int gatherBlocks = (N_NODES + 3) / 4;      // 25000
  const int linBlocks    = (N_NODES + 31) / 32;    // 3125
  const int finBlocks    = 2048;

  // Build dst-CSR (once; reused by both layers)
  hipMemsetAsync(deg, 0, N_NODES * sizeof(int), stream);
  hist_k<<<edgeBlocks, 256, 0, stream>>>(dst, deg);
  scan_partial_k<<<SCAN_BLOCKS, 256, 0, stream>>>(deg, blockSums);
  scan_sums_k<<<1, 128, 0, stream>>>(blockSums, offs);
  scan_final_k<<<SCAN_BLOCKS, 256, 0, stream>>>(deg, blockSums, offs, cursor);
  fill_csr_k<<<edgeBlocks, 256, 0, stream>>>(src, dst, cursor, csr);

  // Layer 1: x --gather--> bufA --linear--> bufB (h1)
  gather_k<<<gatherBlocks, 256, 0, stream>>>(x, offs, csr, bufA);
  linear_relu_k<<<linBlocks, 256, 0, stream>>>(bufA, W1, b1, bufB);

  // Layer 2: bufB --gather--> bufC --linear--> bufA (h2)
  gather_k<<<gatherBlocks, 256, 0, stream>>>(bufB, offs, csr, bufC);
  linear_relu_k<<<linBlocks, 256, 0, stream>>>(bufC, W2, b2, bufA);

  // Final + log_softmax
  final_logsoftmax_k<<<finBlocks, 256, 0, stream>>>(bufA, Wf, bf, out);
}

// Round 7
// 442.894 us; speedup vs baseline: 10.1364x; 1.2439x over previous
//
#include <hip/hip_runtime.h>
#include <math.h>

#define N_NODES 100000
#define N_EDGES 1600000
#define NFEAT 64
#define NCLASS 40

#define SCAN_CHUNK 1024
#define SCAN_BLOCKS ((N_NODES + SCAN_CHUNK - 1) / SCAN_CHUNK)  // 98

// ---------------------------------------------------------------------------
// Pass A: histogram over dst AND record each edge's rank within its node.
// int4-vectorized: 4 edges per thread.
// ---------------------------------------------------------------------------
__global__ __launch_bounds__(256) void hist_rank_k(const int* __restrict__ dst,
                                                   int* __restrict__ deg,
                                                   int* __restrict__ rank) {
  int q = blockIdx.x * 256 + threadIdx.x;  // quad index
  int e = q << 2;
  if (e + 3 < N_EDGES) {
    int4 d = *reinterpret_cast<const int4*>(dst + e);
    int4 r;
    r.x = atomicAdd(&deg[d.x], 1);
    r.y = atomicAdd(&deg[d.y], 1);
    r.z = atomicAdd(&deg[d.z], 1);
    r.w = atomicAdd(&deg[d.w], 1);
    *reinterpret_cast<int4*>(rank + e) = r;
  } else {
    for (int k = e; k < N_EDGES; ++k) rank[k] = atomicAdd(&deg[dst[k]], 1);
  }
}

// Pass 1: per-block chunk sums
__global__ __launch_bounds__(256) void scan_partial_k(
    const int* __restrict__ deg, int* __restrict__ blockSums) {
  __shared__ int red[256];
  int b = blockIdx.x, t = threadIdx.x;
  int base = b * SCAN_CHUNK;
  int s = 0;
  for (int i = t; i < SCAN_CHUNK; i += 256) {
    int idx = base + i;
    if (idx < N_NODES) s += deg[idx];
  }
  red[t] = s;
  __syncthreads();
  for (int off = 128; off; off >>= 1) {
    if (t < off) red[t] += red[t + off];
    __syncthreads();
  }
  if (t == 0) blockSums[b] = red[0];
}

// Pass 2: one small block scans the 98 partials (in place -> exclusive),
// writes offs[N_NODES] = total
__global__ __launch_bounds__(128) void scan_sums_k(int* __restrict__ blockSums,
                                                   int* __restrict__ offs) {
  __shared__ int part[128];
  int t = threadIdx.x;
  int v = (t < SCAN_BLOCKS) ? blockSums[t] : 0;
  part[t] = v;
  __syncthreads();
  for (int off = 1; off < 128; off <<= 1) {
    int add = (t >= off) ? part[t - off] : 0;
    __syncthreads();
    part[t] += add;
    __syncthreads();
  }
  if (t < SCAN_BLOCKS) blockSums[t] = (t == 0) ? 0 : part[t - 1];
  if (t == 127) offs[N_NODES] = part[127];  // == N_EDGES
}

// Pass 3: intra-chunk exclusive scan + block prefix -> offs
__global__ __launch_bounds__(256) void scan_final_k(
    const int* __restrict__ deg, const int* __restrict__ blockOffs,
    int* __restrict__ offs) {
  __shared__ int part[256];
  int b = blockIdx.x, t = threadIdx.x;
  int base = b * SCAN_CHUNK + t * 4;  // thread t owns 4 consecutive elements
  int v0 = 0, v1 = 0, v2 = 0, v3 = 0;
  if (base + 3 < N_NODES) {
    v0 = deg[base]; v1 = deg[base + 1]; v2 = deg[base + 2]; v3 = deg[base + 3];
  } else {
    if (base + 0 < N_NODES) v0 = deg[base + 0];
    if (base + 1 < N_NODES) v1 = deg[base + 1];
    if (base + 2 < N_NODES) v2 = deg[base + 2];
    if (base + 3 < N_NODES) v3 = deg[base + 3];
  }
  part[t] = v0 + v1 + v2 + v3;
  __syncthreads();
  for (int off = 1; off < 256; off <<= 1) {
    int add = (t >= off) ? part[t - off] : 0;
    __syncthreads();
    part[t] += add;
    __syncthreads();
  }
  int run = blockOffs[b] + ((t == 0) ? 0 : part[t - 1]);
  if (base + 0 < N_NODES) { offs[base + 0] = run; run += v0; }
  if (base + 1 < N_NODES) { offs[base + 1] = run; run += v1; }
  if (base + 2 < N_NODES) { offs[base + 2] = run; run += v2; }
  if (base + 3 < N_NODES) { offs[base + 3] = run; run += v3; }
}

// ---------------------------------------------------------------------------
// Pass B: atomic-free CSR fill: csr[offs[d] + rank[e]] = src[e]
// ---------------------------------------------------------------------------
__global__ __launch_bounds__(256) void fill_csr_k(const int* __restrict__ src,
                                                  const int* __restrict__ dst,
                                                  const int* __restrict__ rank,
                                                  const int* __restrict__ offs,
                                                  int* __restrict__ csr) {
  int q = blockIdx.x * 256 + threadIdx.x;
  int e = q << 2;
  if (e + 3 < N_EDGES) {
    int4 s = *reinterpret_cast<const int4*>(src + e);
    int4 d = *reinterpret_cast<const int4*>(dst + e);
    int4 r = *reinterpret_cast<const int4*>(rank + e);
    csr[offs[d.x] + r.x] = s.x;
    csr[offs[d.y] + r.y] = s.y;
    csr[offs[d.z] + r.z] = s.z;
    csr[offs[d.w] + r.w] = s.w;
  } else {
    for (int k = e; k < N_EDGES; ++k) csr[offs[dst[k]] + rank[k]] = src[k];
  }
}

// ---------------------------------------------------------------------------
// Gather: agg[r] = h[r] + sum_{s in N(r)} h[s]
// One wave per node. Lanes = 4 groups x 16 lanes; group g handles every 4th
// edge, lane l covers features [4l, 4l+4) via float4. Inner loop unrolled x2
// -> 8 independent 256B row-read streams in flight per wave.
// ---------------------------------------------------------------------------
__global__ __launch_bounds__(256) void gather_k(
    const float* __restrict__ h, const int* __restrict__ offs,
    const int* __restrict__ csr, float* __restrict__ agg) {
  int t = threadIdx.x;
  int wv = t >> 6;
  int lane = t & 63;
  int g = lane >> 4;   // edge-group 0..3
  int l = lane & 15;   // feature quad 0..15
  int node = blockIdx.x * 4 + wv;
  if (node >= N_NODES) return;

  int beg = offs[node], end = offs[node + 1];
  float ax = 0.f, ay = 0.f, az = 0.f, aw = 0.f;
  int e = beg + g;
  for (; e + 4 < end; e += 8) {
    int s0 = csr[e];
    int s1 = csr[e + 4];
    const float4 v0 =
        *reinterpret_cast<const float4*>(h + (size_t)s0 * NFEAT + (l << 2));
    const float4 v1 =
        *reinterpret_cast<const float4*>(h + (size_t)s1 * NFEAT + (l << 2));
    ax += v0.x + v1.x; ay += v0.y + v1.y;
    az += v0.z + v1.z; aw += v0.w + v1.w;
  }
  if (e < end) {
    int s = csr[e];
    const float4 v =
        *reinterpret_cast<const float4*>(h + (size_t)s * NFEAT + (l << 2));
    ax += v.x; ay += v.y; az += v.z; aw += v.w;
  }
  ax += __shfl_xor(ax, 16); ay += __shfl_xor(ay, 16);
  az += __shfl_xor(az, 16); aw += __shfl_xor(aw, 16);
  ax += __shfl_xor(ax, 32); ay += __shfl_xor(ay, 32);
  az += __shfl_xor(az, 32); aw += __shfl_xor(aw, 32);

  if (g == 0) {
    const float4 self =
        *reinterpret_cast<const float4*>(h + (size_t)node * NFEAT + (l << 2));
    float4 o;
    o.x = ax + self.x; o.y = ay + self.y;
    o.z = az + self.z; o.w = aw + self.w;
    *reinterpret_cast<float4*>(agg + (size_t)node * NFEAT + (l << 2)) = o;
  }
}

// ---------------------------------------------------------------------------
// out[r][c] = relu( sum_k in[r][k] * W[k][c] + b[c] )
// 32-row tile per block, 256 threads: thread t -> col c=t&63, 8 rows.
// ---------------------------------------------------------------------------
__global__ __launch_bounds__(256) void linear_relu_k(
    const float* __restrict__ in, const float* __restrict__ W,
    const float* __restrict__ b, float* __restrict__ out) {
  __shared__ float sIn[32][64];
  __shared__ float sW[64][64];
  int r0 = blockIdx.x * 32;
  int t = threadIdx.x;
  for (int i = t; i < 64 * 64; i += 256) sW[i >> 6][i & 63] = W[i];
  for (int i = t; i < 512; i += 256) {
    int r = i >> 4, q = i & 15;
    float4 v = *reinterpret_cast<const float4*>(
        in + (size_t)(r0 + r) * NFEAT + (q << 2));
    *reinterpret_cast<float4*>(&sIn[r][q << 2]) = v;
  }
  __syncthreads();

  int c = t & 63;
  int rb = t >> 6;  // 0..3 -> rows rb*8..rb*8+8
  float acc[8];
#pragma unroll
  for (int i = 0; i < 8; ++i) acc[i] = 0.f;
#pragma unroll
  for (int k = 0; k < 64; ++k) {
    float wkc = sW[k][c];
#pragma unroll
    for (int i = 0; i < 8; ++i)
      acc[i] = fmaf(sIn[rb * 8 + i][k], wkc, acc[i]);
  }
  float bias = b[c];
#pragma unroll
  for (int i = 0; i < 8; ++i) {
    int gr = r0 + rb * 8 + i;
    out[(size_t)gr * NFEAT + c] = fmaxf(acc[i] + bias, 0.f);
  }
}

// ---------------------------------------------------------------------------
// logits = h @ Wf + bf ; out = log_softmax(logits) — one wave per row,
// grid-stride over rows to amortize the Wf LDS load.
// ---------------------------------------------------------------------------
__global__ __launch_bounds__(256) void final_logsoftmax_k(
    const float* __restrict__ h, const float* __restrict__ Wf,
    const float* __restrict__ bf, float* __restrict__ out) {
  __shared__ float sW[NFEAT * NCLASS];  // [k][c]
  __shared__ float sB[NCLASS];
  int t = threadIdx.x;
  for (int i = t; i < NFEAT * NCLASS; i += 256) sW[i] = Wf[i];
  if (t < NCLASS) sB[t] = bf[t];
  __syncthreads();

  int wave = t >> 6;
  int lane = t & 63;
  int cl = lane < NCLASS ? lane : NCLASS - 1;

  for (int row = blockIdx.x * 4 + wave; row < N_NODES;
       row += gridDim.x * 4) {
    const float* hr = h + (size_t)row * NFEAT;
    float rowval = hr[lane];  // lane k holds h[row][k], coalesced
    float acc = sB[cl];
#pragma unroll
    for (int k = 0; k < NFEAT; ++k) {
      float hv = __shfl(rowval, k);
      acc = fmaf(hv, sW[k * NCLASS + cl], acc);
    }
    float logit = acc;
    float m = (lane < NCLASS) ? logit : -INFINITY;
#pragma unroll
    for (int off = 32; off; off >>= 1) m = fmaxf(m, __shfl_xor(m, off));
    float ex = (lane < NCLASS) ? expf(logit - m) : 0.f;
    float s = ex;
#pragma unroll
    for (int off = 32; off; off >>= 1) s += __shfl_xor(s, off);
    float lse = m + logf(s);
    if (lane < NCLASS) out[(size_t)row * NCLASS + lane] = logit - lse;
  }
}

// ---------------------------------------------------------------------------
extern "C" void kernel_launch(void* const* d_in, const int* in_sizes, int n_in,
                              void* d_out, int out_size, void* d_ws, size_t ws_size,
                              hipStream_t stream) {
  const float* x  = (const float*)d_in[0];
  const int*   ei = (const int*)d_in[1];  // [2, N_EDGES] as int32
  const float* W1 = (const float*)d_in[2];
  const float* b1 = (const float*)d_in[3];
  const float* W2 = (const float*)d_in[4];
  const float* b2 = (const float*)d_in[5];
  const float* Wf = (const float*)d_in[6];
  const float* bf = (const float*)d_in[7];
  float* out = (float*)d_out;

  const int* src = ei;
  const int* dst = ei + N_EDGES;

  const size_t featElems = (size_t)N_NODES * NFEAT;
  float* bufA = (float*)d_ws;            // agg1 / h2
  float* bufB = bufA + featElems;        // h1
  float* bufC = bufB + featElems;        // agg2
  int* deg       = (int*)(bufC + featElems);
  int* offs      = deg + N_NODES;        // N_NODES+1
  int* blockSums = offs + N_NODES + 1;   // 128
  int* rank      = blockSums + 128;      // N_EDGES
  int* csr       = rank + N_EDGES;       // N_EDGES

  const int quadBlocks   = (N_EDGES / 4 + 255) / 256;  // 1563
  const int gatherBlocks = (N_NODES + 3) / 4;          // 25000
  const int linBlocks    = (N_NODES + 31) / 32;        // 3125
  const int finBlocks    = 2048;

  // Build dst-CSR (once; reused by both layers)
  hipMemsetAsync(deg, 0, N_NODES * sizeof(int), stream);
  hist_rank_k<<<quadBlocks, 256, 0, stream>>>(dst, deg, rank);
  scan_partial_k<<<SCAN_BLOCKS, 256, 0, stream>>>(deg, blockSums);
  scan_sums_k<<<1, 128, 0, stream>>>(blockSums, offs);
  scan_final_k<<<SCAN_BLOCKS, 256, 0, stream>>>(deg, blockSums, offs);
  fill_csr_k<<<quadBlocks, 256, 0, stream>>>(src, dst, rank, offs, csr);

  // Layer 1: x --gather--> bufA --linear--> bufB (h1)
  gather_k<<<gatherBlocks, 256, 0, stream>>>(x, offs, csr, bufA);
  linear_relu_k<<<linBlocks, 256, 0, stream>>>(bufA, W1, b1, bufB);

  // Layer 2: bufB --gather--> bufC --linear--> bufA (h2)
  gather_k<<<gatherBlocks, 256, 0, stream>>>(bufB, offs, csr, bufC);
  linear_relu_k<<<linBlocks, 256, 0, stream>>>(bufC, W2, b2, bufA);

  // Final + log_softmax
  final_logsoftmax_k<<<finBlocks, 256, 0, stream>>>(bufA, Wf, bf, out);
}

// Round 8
// 394.352 us; speedup vs baseline: 11.3841x; 1.1231x over previous
//
#include <hip/hip_runtime.h>
#include <math.h>

#define N_NODES 100000
#define N_EDGES 1600000
#define NFEAT 64
#define NCLASS 40

#define SCAN_CHUNK 1024
#define SCAN_BLOCKS ((N_NODES + SCAN_CHUNK - 1) / SCAN_CHUNK)  // 98

// ---------------------------------------------------------------------------
// Pass A: histogram over dst AND record each edge's rank within its node.
// ---------------------------------------------------------------------------
__global__ __launch_bounds__(256) void hist_rank_k(const int* __restrict__ dst,
                                                   int* __restrict__ deg,
                                                   int* __restrict__ rank) {
  int q = blockIdx.x * 256 + threadIdx.x;  // quad index
  int e = q << 2;
  if (e + 3 < N_EDGES) {
    int4 d = *reinterpret_cast<const int4*>(dst + e);
    int4 r;
    r.x = atomicAdd(&deg[d.x], 1);
    r.y = atomicAdd(&deg[d.y], 1);
    r.z = atomicAdd(&deg[d.z], 1);
    r.w = atomicAdd(&deg[d.w], 1);
    *reinterpret_cast<int4*>(rank + e) = r;
  } else {
    for (int k = e; k < N_EDGES; ++k) rank[k] = atomicAdd(&deg[dst[k]], 1);
  }
}

// Pass 1: per-block chunk sums
__global__ __launch_bounds__(256) void scan_partial_k(
    const int* __restrict__ deg, int* __restrict__ blockSums) {
  __shared__ int red[256];
  int b = blockIdx.x, t = threadIdx.x;
  int base = b * SCAN_CHUNK;
  int s = 0;
  for (int i = t; i < SCAN_CHUNK; i += 256) {
    int idx = base + i;
    if (idx < N_NODES) s += deg[idx];
  }
  red[t] = s;
  __syncthreads();
  for (int off = 128; off; off >>= 1) {
    if (t < off) red[t] += red[t + off];
    __syncthreads();
  }
  if (t == 0) blockSums[b] = red[0];
}

// Pass 2: one small block scans the 98 partials
__global__ __launch_bounds__(128) void scan_sums_k(int* __restrict__ blockSums,
                                                   int* __restrict__ offs) {
  __shared__ int part[128];
  int t = threadIdx.x;
  int v = (t < SCAN_BLOCKS) ? blockSums[t] : 0;
  part[t] = v;
  __syncthreads();
  for (int off = 1; off < 128; off <<= 1) {
    int add = (t >= off) ? part[t - off] : 0;
    __syncthreads();
    part[t] += add;
    __syncthreads();
  }
  if (t < SCAN_BLOCKS) blockSums[t] = (t == 0) ? 0 : part[t - 1];
  if (t == 127) offs[N_NODES] = part[127];  // == N_EDGES
}

// Pass 3: intra-chunk exclusive scan + block prefix -> offs
__global__ __launch_bounds__(256) void scan_final_k(
    const int* __restrict__ deg, const int* __restrict__ blockOffs,
    int* __restrict__ offs) {
  __shared__ int part[256];
  int b = blockIdx.x, t = threadIdx.x;
  int base = b * SCAN_CHUNK + t * 4;
  int v0 = 0, v1 = 0, v2 = 0, v3 = 0;
  if (base + 3 < N_NODES) {
    v0 = deg[base]; v1 = deg[base + 1]; v2 = deg[base + 2]; v3 = deg[base + 3];
  } else {
    if (base + 0 < N_NODES) v0 = deg[base + 0];
    if (base + 1 < N_NODES) v1 = deg[base + 1];
    if (base + 2 < N_NODES) v2 = deg[base + 2];
    if (base + 3 < N_NODES) v3 = deg[base + 3];
  }
  part[t] = v0 + v1 + v2 + v3;
  __syncthreads();
  for (int off = 1; off < 256; off <<= 1) {
    int add = (t >= off) ? part[t - off] : 0;
    __syncthreads();
    part[t] += add;
    __syncthreads();
  }
  int run = blockOffs[b] + ((t == 0) ? 0 : part[t - 1]);
  if (base + 0 < N_NODES) { offs[base + 0] = run; run += v0; }
  if (base + 1 < N_NODES) { offs[base + 1] = run; run += v1; }
  if (base + 2 < N_NODES) { offs[base + 2] = run; run += v2; }
  if (base + 3 < N_NODES) { offs[base + 3] = run; run += v3; }
}

// ---------------------------------------------------------------------------
// Pass B: atomic-free CSR fill: csr[offs[d] + rank[e]] = src[e]
// ---------------------------------------------------------------------------
__global__ __launch_bounds__(256) void fill_csr_k(const int* __restrict__ src,
                                                  const int* __restrict__ dst,
                                                  const int* __restrict__ rank,
                                                  const int* __restrict__ offs,
                                                  int* __restrict__ csr) {
  int q = blockIdx.x * 256 + threadIdx.x;
  int e = q << 2;
  if (e + 3 < N_EDGES) {
    int4 s = *reinterpret_cast<const int4*>(src + e);
    int4 d = *reinterpret_cast<const int4*>(dst + e);
    int4 r = *reinterpret_cast<const int4*>(rank + e);
    csr[offs[d.x] + r.x] = s.x;
    csr[offs[d.y] + r.y] = s.y;
    csr[offs[d.z] + r.z] = s.z;
    csr[offs[d.w] + r.w] = s.w;
  } else {
    for (int k = e; k < N_EDGES; ++k) csr[offs[dst[k]] + rank[k]] = src[k];
  }
}

// ---------------------------------------------------------------------------
// Gather: agg[r] = h[r] + sum_{s in N(r)} h[s]
// One wave per node; 4 edge-groups x 16 lanes x float4; unroll x2.
// ---------------------------------------------------------------------------
__global__ __launch_bounds__(256) void gather_k(
    const float* __restrict__ h, const int* __restrict__ offs,
    const int* __restrict__ csr, float* __restrict__ agg) {
  int t = threadIdx.x;
  int wv = t >> 6;
  int lane = t & 63;
  int g = lane >> 4;   // edge-group 0..3
  int l = lane & 15;   // feature quad 0..15
  int node = blockIdx.x * 4 + wv;
  if (node >= N_NODES) return;

  int beg = offs[node], end = offs[node + 1];
  float ax = 0.f, ay = 0.f, az = 0.f, aw = 0.f;
  int e = beg + g;
  for (; e + 4 < end; e += 8) {
    int s0 = csr[e];
    int s1 = csr[e + 4];
    const float4 v0 =
        *reinterpret_cast<const float4*>(h + (size_t)s0 * NFEAT + (l << 2));
    const float4 v1 =
        *reinterpret_cast<const float4*>(h + (size_t)s1 * NFEAT + (l << 2));
    ax += v0.x + v1.x; ay += v0.y + v1.y;
    az += v0.z + v1.z; aw += v0.w + v1.w;
  }
  if (e < end) {
    int s = csr[e];
    const float4 v =
        *reinterpret_cast<const float4*>(h + (size_t)s * NFEAT + (l << 2));
    ax += v.x; ay += v.y; az += v.z; aw += v.w;
  }
  ax += __shfl_xor(ax, 16); ay += __shfl_xor(ay, 16);
  az += __shfl_xor(az, 16); aw += __shfl_xor(aw, 16);
  ax += __shfl_xor(ax, 32); ay += __shfl_xor(ay, 32);
  az += __shfl_xor(az, 32); aw += __shfl_xor(aw, 32);

  if (g == 0) {
    const float4 self =
        *reinterpret_cast<const float4*>(h + (size_t)node * NFEAT + (l << 2));
    float4 o;
    o.x = ax + self.x; o.y = ay + self.y;
    o.z = az + self.z; o.w = aw + self.w;
    *reinterpret_cast<float4*>(agg + (size_t)node * NFEAT + (l << 2)) = o;
  }
}

// ---------------------------------------------------------------------------
// Layer-1 linear: out[r][c] = relu( sum_k in[r][k] * W[k][c] + b[c] )
// ---------------------------------------------------------------------------
__global__ __launch_bounds__(256) void linear_relu_k(
    const float* __restrict__ in, const float* __restrict__ W,
    const float* __restrict__ b, float* __restrict__ out) {
  __shared__ float sIn[32][64];
  __shared__ float sW[64][64];
  int r0 = blockIdx.x * 32;
  int t = threadIdx.x;
  for (int i = t; i < 64 * 64; i += 256) sW[i >> 6][i & 63] = W[i];
  for (int i = t; i < 512; i += 256) {
    int r = i >> 4, q = i & 15;
    float4 v = *reinterpret_cast<const float4*>(
        in + (size_t)(r0 + r) * NFEAT + (q << 2));
    *reinterpret_cast<float4*>(&sIn[r][q << 2]) = v;
  }
  __syncthreads();

  int c = t & 63;
  int rb = t >> 6;
  float acc[8];
#pragma unroll
  for (int i = 0; i < 8; ++i) acc[i] = 0.f;
#pragma unroll
  for (int k = 0; k < 64; ++k) {
    float wkc = sW[k][c];
#pragma unroll
    for (int i = 0; i < 8; ++i)
      acc[i] = fmaf(sIn[rb * 8 + i][k], wkc, acc[i]);
  }
  float bias = b[c];
#pragma unroll
  for (int i = 0; i < 8; ++i) {
    int gr = r0 + rb * 8 + i;
    out[(size_t)gr * NFEAT + c] = fmaxf(acc[i] + bias, 0.f);
  }
}

// ---------------------------------------------------------------------------
// Fused layer-2 linear + final linear + log_softmax.
// Block = 32 rows, 256 threads (4 waves).
// P1: h2 = relu(agg@W2+b2) -> sH. P2: logits = h2@Wf+bf -> sLg.
// P3: per-row logsumexp; coalesced 32x40 output write.
// ---------------------------------------------------------------------------
__global__ __launch_bounds__(256) void fused_l2_final_k(
    const float* __restrict__ in, const float* __restrict__ W2,
    const float* __restrict__ b2, const float* __restrict__ Wf,
    const float* __restrict__ bf, float* __restrict__ out) {
  __shared__ float sIn[32][64];
  __shared__ float sW[64][64];
  __shared__ float sWf[64][NCLASS];
  __shared__ float sH[32][65];
  __shared__ float sLg[32][41];
  __shared__ float sLse[32];

  int r0 = blockIdx.x * 32;
  int t = threadIdx.x;
  int c = t & 63;
  int rb = t >> 6;  // wave id 0..3

  for (int i = t; i < 64 * 64; i += 256) sW[i >> 6][i & 63] = W2[i];
  for (int i = t; i < 64 * NCLASS; i += 256) sWf[i / NCLASS][i % NCLASS] = Wf[i];
  for (int i = t; i < 512; i += 256) {
    int r = i >> 4, q = i & 15;
    float4 v = *reinterpret_cast<const float4*>(
        in + (size_t)(r0 + r) * NFEAT + (q << 2));
    *reinterpret_cast<float4*>(&sIn[r][q << 2]) = v;
  }
  __syncthreads();

  // P1: h2 tile (thread: col c, rows rb*8..+8)
  float acc[8];
#pragma unroll
  for (int i = 0; i < 8; ++i) acc[i] = 0.f;
#pragma unroll
  for (int k = 0; k < 64; ++k) {
    float wkc = sW[k][c];
#pragma unroll
    for (int i = 0; i < 8; ++i)
      acc[i] = fmaf(sIn[rb * 8 + i][k], wkc, acc[i]);
  }
  float bias = b2[c];
#pragma unroll
  for (int i = 0; i < 8; ++i)
    sH[rb * 8 + i][c] = fmaxf(acc[i] + bias, 0.f);
  __syncthreads();

  // P2: logits (thread: col c (<NCLASS), rows rb*8..+8).
  // sH reads are wave-broadcast; sWf reads at most 2-way (free).
  if (c < NCLASS) {
    float lg[8];
    float bfc = bf[c];
#pragma unroll
    for (int i = 0; i < 8; ++i) lg[i] = bfc;
#pragma unroll
    for (int k = 0; k < 64; ++k) {
      float wkc = sWf[k][c];
#pragma unroll
      for (int i = 0; i < 8; ++i)
        lg[i] = fmaf(sH[rb * 8 + i][k], wkc, lg[i]);
    }
#pragma unroll
    for (int i = 0; i < 8; ++i) sLg[rb * 8 + i][c] = lg[i];
  }
  __syncthreads();

  // P3: per-row logsumexp (threads 0..31, one row each; stride-41 conflict-free)
  if (t < 32) {
    float m = -INFINITY;
#pragma unroll
    for (int j = 0; j < NCLASS; ++j) m = fmaxf(m, sLg[t][j]);
    float s = 0.f;
#pragma unroll
    for (int j = 0; j < NCLASS; ++j) s += expf(sLg[t][j] - m);
    sLse[t] = m + logf(s);
  }
  __syncthreads();

  // Coalesced output: block's 32 rows = 1280 contiguous floats
  for (int i = t; i < 32 * NCLASS; i += 256) {
    int r = i / NCLASS, cc = i - r * NCLASS;
    out[(size_t)(r0 + r) * NCLASS + cc] = sLg[r][cc] - sLse[r];
  }
}

// ---------------------------------------------------------------------------
extern "C" void kernel_launch(void* const* d_in, const int* in_sizes, int n_in,
                              void* d_out, int out_size, void* d_ws, size_t ws_size,
                              hipStream_t stream) {
  const float* x  = (const float*)d_in[0];
  const int*   ei = (const int*)d_in[1];  // [2, N_EDGES] as int32
  const float* W1 = (const float*)d_in[2];
  const float* b1 = (const float*)d_in[3];
  const float* W2 = (const float*)d_in[4];
  const float* b2 = (const float*)d_in[5];
  const float* Wf = (const float*)d_in[6];
  const float* bf = (const float*)d_in[7];
  float* out = (float*)d_out;

  const int* src = ei;
  const int* dst = ei + N_EDGES;

  const size_t featElems = (size_t)N_NODES * NFEAT;
  float* bufA = (float*)d_ws;            // agg1
  float* bufB = bufA + featElems;        // h1
  float* bufC = bufB + featElems;        // agg2
  int* deg       = (int*)(bufC + featElems);
  int* offs      = deg + N_NODES;        // N_NODES+1
  int* blockSums = offs + N_NODES + 1;   // 128
  int* rank      = blockSums + 128;      // N_EDGES
  int* csr       = rank + N_EDGES;       // N_EDGES

  const int quadBlocks   = (N_EDGES / 4 + 255) / 256;  // 1563
  const int gatherBlocks = (N_NODES + 3) / 4;          // 25000
  const int linBlocks    = (N_NODES + 31) / 32;        // 3125

  // Build dst-CSR (once; reused by both layers)
  hipMemsetAsync(deg, 0, N_NODES * sizeof(int), stream);
  hist_rank_k<<<quadBlocks, 256, 0, stream>>>(dst, deg, rank);
  scan_partial_k<<<SCAN_BLOCKS, 256, 0, stream>>>(deg, blockSums);
  scan_sums_k<<<1, 128, 0, stream>>>(blockSums, offs);
  scan_final_k<<<SCAN_BLOCKS, 256, 0, stream>>>(deg, blockSums, offs);
  fill_csr_k<<<quadBlocks, 256, 0, stream>>>(src, dst, rank, offs, csr);

  // Layer 1: x --gather--> bufA --linear--> bufB (h1)
  gather_k<<<gatherBlocks, 256, 0, stream>>>(x, offs, csr, bufA);
  linear_relu_k<<<linBlocks, 256, 0, stream>>>(bufA, W1, b1, bufB);

  // Layer 2 + final + logsoftmax, fused:
  gather_k<<<gatherBlocks, 256, 0, stream>>>(bufB, offs, csr, bufC);
  fused_l2_final_k<<<linBlocks, 256, 0, stream>>>(bufC, W2, b2, Wf, bf, out);
}

// Round 9
// 367.669 us; speedup vs baseline: 12.2103x; 1.0726x over previous
//
#include <hip/hip_runtime.h>
#include <math.h>

#define N_NODES 100000
#define N_EDGES 1600000
#define NFEAT 64
#define NCLASS 40

#define SCAN_CHUNK 1024
#define SCAN_BLOCKS ((N_NODES + SCAN_CHUNK - 1) / SCAN_CHUNK)  // 98

__device__ __forceinline__ float bf2f(unsigned short u) {
  return __uint_as_float(((unsigned int)u) << 16);
}
__device__ __forceinline__ unsigned short f2bf(float f) {
  unsigned int u = __float_as_uint(f);
  u += 0x7FFFu + ((u >> 16) & 1u);  // RNE
  return (unsigned short)(u >> 16);
}

// ---------------------------------------------------------------------------
// Pass A: histogram over dst + per-edge rank. 1 edge/thread (max parallel
// atomics; the int4 variant serialized 4 atomic latencies per thread).
// ---------------------------------------------------------------------------
__global__ __launch_bounds__(256) void hist_rank_k(const int* __restrict__ dst,
                                                   int* __restrict__ deg,
                                                   int* __restrict__ rank) {
  int e = blockIdx.x * 256 + threadIdx.x;
  if (e < N_EDGES) rank[e] = atomicAdd(&deg[dst[e]], 1);
}

// Pass 1: per-block chunk sums
__global__ __launch_bounds__(256) void scan_partial_k(
    const int* __restrict__ deg, int* __restrict__ blockSums) {
  __shared__ int red[256];
  int b = blockIdx.x, t = threadIdx.x;
  int base = b * SCAN_CHUNK;
  int s = 0;
  for (int i = t; i < SCAN_CHUNK; i += 256) {
    int idx = base + i;
    if (idx < N_NODES) s += deg[idx];
  }
  red[t] = s;
  __syncthreads();
  for (int off = 128; off; off >>= 1) {
    if (t < off) red[t] += red[t + off];
    __syncthreads();
  }
  if (t == 0) blockSums[b] = red[0];
}

// Pass 2: one small block scans the 98 partials
__global__ __launch_bounds__(128) void scan_sums_k(int* __restrict__ blockSums,
                                                   int* __restrict__ offs) {
  __shared__ int part[128];
  int t = threadIdx.x;
  int v = (t < SCAN_BLOCKS) ? blockSums[t] : 0;
  part[t] = v;
  __syncthreads();
  for (int off = 1; off < 128; off <<= 1) {
    int add = (t >= off) ? part[t - off] : 0;
    __syncthreads();
    part[t] += add;
    __syncthreads();
  }
  if (t < SCAN_BLOCKS) blockSums[t] = (t == 0) ? 0 : part[t - 1];
  if (t == 127) offs[N_NODES] = part[127];  // == N_EDGES
}

// Pass 3: intra-chunk exclusive scan + block prefix -> offs
__global__ __launch_bounds__(256) void scan_final_k(
    const int* __restrict__ deg, const int* __restrict__ blockOffs,
    int* __restrict__ offs) {
  __shared__ int part[256];
  int b = blockIdx.x, t = threadIdx.x;
  int base = b * SCAN_CHUNK + t * 4;
  int v0 = 0, v1 = 0, v2 = 0, v3 = 0;
  if (base + 3 < N_NODES) {
    v0 = deg[base]; v1 = deg[base + 1]; v2 = deg[base + 2]; v3 = deg[base + 3];
  } else {
    if (base + 0 < N_NODES) v0 = deg[base + 0];
    if (base + 1 < N_NODES) v1 = deg[base + 1];
    if (base + 2 < N_NODES) v2 = deg[base + 2];
    if (base + 3 < N_NODES) v3 = deg[base + 3];
  }
  part[t] = v0 + v1 + v2 + v3;
  __syncthreads();
  for (int off = 1; off < 256; off <<= 1) {
    int add = (t >= off) ? part[t - off] : 0;
    __syncthreads();
    part[t] += add;
    __syncthreads();
  }
  int run = blockOffs[b] + ((t == 0) ? 0 : part[t - 1]);
  if (base + 0 < N_NODES) { offs[base + 0] = run; run += v0; }
  if (base + 1 < N_NODES) { offs[base + 1] = run; run += v1; }
  if (base + 2 < N_NODES) { offs[base + 2] = run; run += v2; }
  if (base + 3 < N_NODES) { offs[base + 3] = run; run += v3; }
}

// ---------------------------------------------------------------------------
// Pass B: atomic-free CSR fill: csr[offs[d] + rank[e]] = src[e]
// ---------------------------------------------------------------------------
__global__ __launch_bounds__(256) void fill_csr_k(const int* __restrict__ src,
                                                  const int* __restrict__ dst,
                                                  const int* __restrict__ rank,
                                                  const int* __restrict__ offs,
                                                  int* __restrict__ csr) {
  int q = blockIdx.x * 256 + threadIdx.x;
  int e = q << 2;
  if (e + 3 < N_EDGES) {
    int4 s = *reinterpret_cast<const int4*>(src + e);
    int4 d = *reinterpret_cast<const int4*>(dst + e);
    int4 r = *reinterpret_cast<const int4*>(rank + e);
    csr[offs[d.x] + r.x] = s.x;
    csr[offs[d.y] + r.y] = s.y;
    csr[offs[d.z] + r.z] = s.z;
    csr[offs[d.w] + r.w] = s.w;
  } else {
    for (int k = e; k < N_EDGES; ++k) csr[offs[dst[k]] + rank[k]] = src[k];
  }
}

// ---------------------------------------------------------------------------
// Convert fp32 feature matrix -> bf16 (RNE)
// ---------------------------------------------------------------------------
__global__ __launch_bounds__(256) void convert_bf16_k(
    const float* __restrict__ in, unsigned short* __restrict__ out) {
  int q = blockIdx.x * 256 + threadIdx.x;  // quad index, total 1.6M
  const int NQ = N_NODES * NFEAT / 4;
  if (q < NQ) {
    float4 v = reinterpret_cast<const float4*>(in)[q];
    ushort4 o;
    o.x = f2bf(v.x); o.y = f2bf(v.y); o.z = f2bf(v.z); o.w = f2bf(v.w);
    reinterpret_cast<ushort4*>(out)[q] = o;
  }
}

// ---------------------------------------------------------------------------
// Gather (bf16 input, fp32 accum/output): agg[r] = h[r] + sum_{s in N(r)} h[s]
// One wave per node; 4 edge-groups x 16 lanes; lane covers 4 feats (8B bf16x4);
// unroll x2 -> 8 independent 128B row-read streams per wave.
// ---------------------------------------------------------------------------
__global__ __launch_bounds__(256) void gather_b_k(
    const unsigned short* __restrict__ hb, const int* __restrict__ offs,
    const int* __restrict__ csr, float* __restrict__ agg) {
  int t = threadIdx.x;
  int wv = t >> 6;
  int lane = t & 63;
  int g = lane >> 4;   // edge-group 0..3
  int l = lane & 15;   // feature quad 0..15
  int node = blockIdx.x * 4 + wv;
  if (node >= N_NODES) return;

  int beg = offs[node], end = offs[node + 1];
  float a0 = 0.f, a1 = 0.f, a2 = 0.f, a3 = 0.f;
  int e = beg + g;
  for (; e + 4 < end; e += 8) {
    int s0 = csr[e];
    int s1 = csr[e + 4];
    ushort4 u0 = *reinterpret_cast<const ushort4*>(hb + (size_t)s0 * NFEAT + (l << 2));
    ushort4 u1 = *reinterpret_cast<const ushort4*>(hb + (size_t)s1 * NFEAT + (l << 2));
    a0 += bf2f(u0.x) + bf2f(u1.x);
    a1 += bf2f(u0.y) + bf2f(u1.y);
    a2 += bf2f(u0.z) + bf2f(u1.z);
    a3 += bf2f(u0.w) + bf2f(u1.w);
  }
  if (e < end) {
    int s = csr[e];
    ushort4 u = *reinterpret_cast<const ushort4*>(hb + (size_t)s * NFEAT + (l << 2));
    a0 += bf2f(u.x); a1 += bf2f(u.y); a2 += bf2f(u.z); a3 += bf2f(u.w);
  }
  a0 += __shfl_xor(a0, 16); a1 += __shfl_xor(a1, 16);
  a2 += __shfl_xor(a2, 16); a3 += __shfl_xor(a3, 16);
  a0 += __shfl_xor(a0, 32); a1 += __shfl_xor(a1, 32);
  a2 += __shfl_xor(a2, 32); a3 += __shfl_xor(a3, 32);

  if (g == 0) {
    ushort4 u = *reinterpret_cast<const ushort4*>(hb + (size_t)node * NFEAT + (l << 2));
    float4 o;
    o.x = a0 + bf2f(u.x); o.y = a1 + bf2f(u.y);
    o.z = a2 + bf2f(u.z); o.w = a3 + bf2f(u.w);
    *reinterpret_cast<float4*>(agg + (size_t)node * NFEAT + (l << 2)) = o;
  }
}

// ---------------------------------------------------------------------------
// Layer-1 linear (fp32 in, bf16 out): out[r][c] = relu(sum_k in[r][k]W[k][c]+b[c])
// Transposed W in LDS -> float4 k-reads: 144 b128 ds_reads/thread vs 576 b32.
// ---------------------------------------------------------------------------
__global__ __launch_bounds__(256) void linear_relu_b_k(
    const float* __restrict__ in, const float* __restrict__ W,
    const float* __restrict__ b, unsigned short* __restrict__ outb) {
  __shared__ float sIn[32][68];
  __shared__ float sWT[64][68];  // sWT[c][k]
  int r0 = blockIdx.x * 32;
  int t = threadIdx.x;
  for (int i = t; i < 64 * 64; i += 256) {
    int k = i >> 6, c = i & 63;
    sWT[c][k] = W[i];
  }
  for (int i = t; i < 512; i += 256) {
    int r = i >> 4, q = i & 15;
    float4 v = *reinterpret_cast<const float4*>(
        in + (size_t)(r0 + r) * NFEAT + (q << 2));
    *reinterpret_cast<float4*>(&sIn[r][q << 2]) = v;
  }
  __syncthreads();

  int c = t & 63;
  int rb = t >> 6;
  float acc[8];
#pragma unroll
  for (int i = 0; i < 8; ++i) acc[i] = 0.f;
#pragma unroll
  for (int kq = 0; kq < 16; ++kq) {
    float4 w = *reinterpret_cast<const float4*>(&sWT[c][kq << 2]);
#pragma unroll
    for (int i = 0; i < 8; ++i) {
      float4 v = *reinterpret_cast<const float4*>(&sIn[rb * 8 + i][kq << 2]);
      acc[i] = fmaf(v.x, w.x, fmaf(v.y, w.y, fmaf(v.z, w.z, fmaf(v.w, w.w, acc[i]))));
    }
  }
  float bias = b[c];
#pragma unroll
  for (int i = 0; i < 8; ++i) {
    int gr = r0 + rb * 8 + i;
    outb[(size_t)gr * NFEAT + c] = f2bf(fmaxf(acc[i] + bias, 0.f));
  }
}

// ---------------------------------------------------------------------------
// Fused layer-2 linear + final linear + log_softmax (fp32 agg in).
// Same transposed-W float4 structure for both GEMM phases.
// sLg reuses sIn's LDS (dead after P1).
// ---------------------------------------------------------------------------
__global__ __launch_bounds__(256) void fused_l2_final_k(
    const float* __restrict__ in, const float* __restrict__ W2,
    const float* __restrict__ b2, const float* __restrict__ Wf,
    const float* __restrict__ bf, float* __restrict__ out) {
  __shared__ float sIn[32][68];
  __shared__ float sWT[64][68];      // W2^T
  __shared__ float sWfT[NCLASS][68]; // Wf^T
  __shared__ float sH[32][68];
  __shared__ float sLse[32];
  float (*sLg)[41] = reinterpret_cast<float(*)[41]>(&sIn[0][0]);  // alias

  int r0 = blockIdx.x * 32;
  int t = threadIdx.x;
  int c = t & 63;
  int rb = t >> 6;

  for (int i = t; i < 64 * 64; i += 256) {
    int k = i >> 6, cc = i & 63;
    sWT[cc][k] = W2[i];
  }
  for (int i = t; i < 64 * NCLASS; i += 256) {
    int k = i / NCLASS, cc = i - k * NCLASS;
    sWfT[cc][k] = Wf[i];
  }
  for (int i = t; i < 512; i += 256) {
    int r = i >> 4, q = i & 15;
    float4 v = *reinterpret_cast<const float4*>(
        in + (size_t)(r0 + r) * NFEAT + (q << 2));
    *reinterpret_cast<float4*>(&sIn[r][q << 2]) = v;
  }
  __syncthreads();

  // P1: h2 = relu(agg @ W2 + b2) -> sH
  float acc[8];
#pragma unroll
  for (int i = 0; i < 8; ++i) acc[i] = 0.f;
#pragma unroll
  for (int kq = 0; kq < 16; ++kq) {
    float4 w = *reinterpret_cast<const float4*>(&sWT[c][kq << 2]);
#pragma unroll
    for (int i = 0; i < 8; ++i) {
      float4 v = *reinterpret_cast<const float4*>(&sIn[rb * 8 + i][kq << 2]);
      acc[i] = fmaf(v.x, w.x, fmaf(v.y, w.y, fmaf(v.z, w.z, fmaf(v.w, w.w, acc[i]))));
    }
  }
  float bias = b2[c];
#pragma unroll
  for (int i = 0; i < 8; ++i)
    sH[rb * 8 + i][c] = fmaxf(acc[i] + bias, 0.f);
  __syncthreads();

  // P2: logits = h2 @ Wf + bf -> sLg (aliases sIn; sIn dead, barrier above)
  if (c < NCLASS) {
    float lg[8];
    float bfc = bf[c];
#pragma unroll
    for (int i = 0; i < 8; ++i) lg[i] = bfc;
#pragma unroll
    for (int kq = 0; kq < 16; ++kq) {
      float4 w = *reinterpret_cast<const float4*>(&sWfT[c][kq << 2]);
#pragma unroll
      for (int i = 0; i < 8; ++i) {
        float4 v = *reinterpret_cast<const float4*>(&sH[rb * 8 + i][kq << 2]);
        lg[i] = fmaf(v.x, w.x, fmaf(v.y, w.y, fmaf(v.z, w.z, fmaf(v.w, w.w, lg[i]))));
      }
    }
#pragma unroll
    for (int i = 0; i < 8; ++i) sLg[rb * 8 + i][c] = lg[i];
  }
  __syncthreads();

  // P3: per-row logsumexp
  if (t < 32) {
    float m = -INFINITY;
#pragma unroll
    for (int j = 0; j < NCLASS; ++j) m = fmaxf(m, sLg[t][j]);
    float s = 0.f;
#pragma unroll
    for (int j = 0; j < NCLASS; ++j) s += expf(sLg[t][j] - m);
    sLse[t] = m + logf(s);
  }
  __syncthreads();

  // Coalesced output: 32 rows = 1280 contiguous floats
  for (int i = t; i < 32 * NCLASS; i += 256) {
    int r = i / NCLASS, cc = i - r * NCLASS;
    out[(size_t)(r0 + r) * NCLASS + cc] = sLg[r][cc] - sLse[r];
  }
}

// ---------------------------------------------------------------------------
extern "C" void kernel_launch(void* const* d_in, const int* in_sizes, int n_in,
                              void* d_out, int out_size, void* d_ws, size_t ws_size,
                              hipStream_t stream) {
  const float* x  = (const float*)d_in[0];
  const int*   ei = (const int*)d_in[1];  // [2, N_EDGES] as int32
  const float* W1 = (const float*)d_in[2];
  const float* b1 = (const float*)d_in[3];
  const float* W2 = (const float*)d_in[4];
  const float* b2 = (const float*)d_in[5];
  const float* Wf = (const float*)d_in[6];
  const float* bf = (const float*)d_in[7];
  float* out = (float*)d_out;

  const int* src = ei;
  const int* dst = ei + N_EDGES;

  const size_t featElems = (size_t)N_NODES * NFEAT;  // 6.4M
  float* bufA = (float*)d_ws;                   // agg1 (fp32)
  float* bufC = bufA + featElems;               // agg2 (fp32)
  unsigned short* xb  = (unsigned short*)(bufC + featElems);  // bf16 x
  unsigned short* h1b = xb + featElems;                       // bf16 h1
  int* deg       = (int*)(h1b + featElems);
  int* offs      = deg + N_NODES;               // N_NODES+1
  int* blockSums = offs + N_NODES + 1;          // 128
  int* rank      = blockSums + 128;             // N_EDGES
  int* csr       = rank + N_EDGES;              // N_EDGES

  const int edgeBlocks   = (N_EDGES + 255) / 256;      // 6250
  const int quadBlocks   = (N_EDGES / 4 + 255) / 256;  // 1563
  const int cvtBlocks    = (N_NODES * NFEAT / 4 + 255) / 256;  // 6250
  const int gatherBlocks = (N_NODES + 3) / 4;          // 25000
  const int linBlocks    = (N_NODES + 31) / 32;        // 3125

  // Build dst-CSR
  hipMemsetAsync(deg, 0, N_NODES * sizeof(int), stream);
  hist_rank_k<<<edgeBlocks, 256, 0, stream>>>(dst, deg, rank);
  scan_partial_k<<<SCAN_BLOCKS, 256, 0, stream>>>(deg, blockSums);
  scan_sums_k<<<1, 128, 0, stream>>>(blockSums, offs);
  scan_final_k<<<SCAN_BLOCKS, 256, 0, stream>>>(deg, blockSums, offs);
  fill_csr_k<<<quadBlocks, 256, 0, stream>>>(src, dst, rank, offs, csr);

  // x -> bf16
  convert_bf16_k<<<cvtBlocks, 256, 0, stream>>>(x, xb);

  // Layer 1: xb --gather--> bufA --linear--> h1b (bf16)
  gather_b_k<<<gatherBlocks, 256, 0, stream>>>(xb, offs, csr, bufA);
  linear_relu_b_k<<<linBlocks, 256, 0, stream>>>(bufA, W1, b1, h1b);

  // Layer 2 + final + logsoftmax
  gather_b_k<<<gatherBlocks, 256, 0, stream>>>(h1b, offs, csr, bufC);
  fused_l2_final_k<<<linBlocks, 256, 0, stream>>>(bufC, W2, b2, Wf, bf, out);
}